// Round 26
// baseline (251.048 us; speedup 1.0000x reference)
//
#include <hip/hip_runtime.h>
#include <math.h>

namespace {

constexpr int NN  = 50000;   // nodes
constexpr int NE  = 800000;  // edges
constexpr int FIN = 128;     // in features
constexpr int CH  = 96;      // conv hidden
constexpr int LH  = 64;      // lin hidden
constexpr int NC  = 10;      // classes
constexpr int NG  = 128;     // graphs
constexpr int ELLC = 64;     // per-node edge cap (P[deg>64] ~ 1e-15 for Poisson(16))
constexpr int NSL  = 8;      // dest slices (one per XCD)
constexpr int SLN  = NN / NSL;              // 6250 nodes per slice (exact)
constexpr int NBS  = (SLN + 255) / 256;     // 25 node-blocks per slice
constexpr int NBC  = 32;     // edge chunks per slice
constexpr int CH_E = NE / NBC;              // 25000 edges per chunk (exact)

typedef unsigned short u16;
typedef unsigned int u32;
typedef __attribute__((ext_vector_type(8))) _Float16 half8;
typedef __attribute__((ext_vector_type(8))) _Float16 f16x8;
typedef __attribute__((ext_vector_type(4))) float f32x4;
typedef __attribute__((ext_vector_type(4))) int i32x4;   // nontemporal-compatible

__device__ __forceinline__ int round8(int c) { return (c + 7) & ~7; }
__device__ __forceinline__ int bucket_of(int craw) { return min(round8(craw) >> 3, 63); }

// ---------------- graph-structure build (once per call) ----------------
// Atomic-free, slice-major rank space. cntmat planes are u16 (counts <= 64).

__global__ __launch_bounds__(1024) void k_cntA(const int* __restrict__ ei,
                                               const float* __restrict__ ew,
                                               u16* __restrict__ cntmat,
                                               float* __restrict__ wsummat) {
  __shared__ int lh[SLN];
  __shared__ float lw[SLN];
  int s = blockIdx.x & 7, b = blockIdx.x >> 3;
  int lo = s * SLN;
  int t = threadIdx.x;
  for (int i = t; i < SLN; i += 1024) { lh[i] = 0; lw[i] = 0.f; }
  __syncthreads();
  int e0 = b * CH_E, e1 = e0 + CH_E;
  for (int e = e0 + t; e < e1; e += 1024) {
    int c = ei[NE + e] - lo;
    if ((unsigned)c < (unsigned)SLN) {
      atomicAdd(&lh[c], 1);        // LDS atomic
      atomicAdd(&lw[c], ew[e]);    // LDS float atomic
    }
  }
  __syncthreads();
  u16* dst = cntmat + (size_t)blockIdx.x * SLN;
  float* dw = wsummat + (size_t)blockIdx.x * SLN;
  for (int i = t; i < SLN; i += 1024) { dst[i] = (u16)lh[i]; dw[i] = lw[i]; }
}

__global__ void k_cntB(u16* __restrict__ cntmat, const float* __restrict__ wsummat,
                       int* __restrict__ cnt, float* __restrict__ dinv_n,
                       int* __restrict__ hist2d,
                       const int* __restrict__ batch, int* __restrict__ gstart) {
  __shared__ int lh[64];
  int s = blockIdx.x / NBS, blk = blockIdx.x - s * NBS;
  int t = threadIdx.x;
  if (t < 64) lh[t] = 0;
  __syncthreads();
  int i = blk * 256 + t;  // within slice
  if (i < SLN) {
    int n = s * SLN + i;
    int run = 0;
    float ws = 0.f;
    for (int b = 0; b < NBC; ++b) {
      size_t off = ((size_t)(b * 8 + s)) * SLN + i;
      int v = cntmat[off];
      cntmat[off] = (u16)min(run, 255);  // exclusive base (<=64 always)
      run += v;
      ws += wsummat[off];
    }
    cnt[n] = run;
    dinv_n[n] = 1.0f / sqrtf(1.0f + ws);  // self-loop weight 1; >= 1 always
    atomicAdd(&lh[bucket_of(min(run, ELLC))], 1);  // LDS atomic
    int g = batch[n];
    if (n == 0 || batch[n - 1] != g) gstart[g] = n;
    if (n == NN - 1) gstart[NG] = NN;
  }
  __syncthreads();
  if (t < 64) hist2d[(s * 64 + t) * NBS + blk] = lh[t];
}

__global__ __launch_bounds__(256) void k_place(const int* __restrict__ cnt,
                                               const int* __restrict__ hist2d,
                                               const float* __restrict__ dinv_n,
                                               int* __restrict__ perm,
                                               int* __restrict__ irank,
                                               int* __restrict__ cntr,
                                               int* __restrict__ offs_r,
                                               float* __restrict__ dinv_r,
                                               int* __restrict__ ebase_n,
                                               int2* __restrict__ srcinfo,
                                               u32* __restrict__ epk) {
  constexpr int TOT = NSL * 64 * NBS;  // 12800
  __shared__ int vals[TOT];            // 51.2KB
  __shared__ int tot[NSL][64];
  __shared__ int rankStartS[NSL][64];
  __shared__ int edgeBaseS[NSL][64];
  __shared__ int sliceEB[NSL];
  __shared__ int sB[64];
  __shared__ int lc[64];
  int s = blockIdx.x / NBS, blk = blockIdx.x - s * NBS;
  int t = threadIdx.x;
  if (t < 64) lc[t] = 0;
  for (int i = t; i < TOT; i += 256) vals[i] = hist2d[i];
  __syncthreads();
  if (t < 64) {
    for (int ss = 0; ss < NSL; ++ss) {
      int v = 0;
      for (int k = 0; k < NBS; ++k) v += vals[(ss * 64 + t) * NBS + k];
      tot[ss][t] = v;
    }
  }
  __syncthreads();
  if (t < NSL) {
    int run = 0, erun = 0;
    for (int b = 0; b < 64; ++b) {
      rankStartS[t][b] = run;
      edgeBaseS[t][b] = erun;
      run += tot[t][b];
      erun += 8 * b * tot[t][b];
    }
    sliceEB[t] = erun;  // total padded edges of slice t (temp)
  }
  __syncthreads();
  if (t == 0) {
    int run = 0;
    for (int ss = 0; ss < NSL; ++ss) { int v = sliceEB[ss]; sliceEB[ss] = run; run += v; }
  }
  if (t < 64) {
    int v = rankStartS[s][t];
    for (int k = 0; k < blk; ++k) v += vals[(s * 64 + t) * NBS + k];
    sB[t] = v;  // this block's within-slice rank start for bucket t
  }
  __syncthreads();
  int i = blk * 256 + t;
  if (i < SLN) {
    int n = s * SLN + i;
    int c = min(cnt[n], ELLC);
    int b = bucket_of(c);
    int r = atomicAdd(&lc[b], 1);             // LDS atomic
    int wr = sB[b] + r;                       // within-slice rank
    int rank = s * SLN + wr;
    int offs = sliceEB[s] + edgeBaseS[s][b] + 8 * b * (wr - rankStartS[s][b]);
    perm[rank] = n;
    irank[n] = rank;
    cntr[rank] = 8 * b;                       // == round8(c)
    offs_r[rank] = offs;
    dinv_r[rank] = dinv_n[n];
    ebase_n[n] = offs;
    srcinfo[n] = make_int2(rank, __float_as_int(dinv_n[n]));
    // zero this node's pad slots (avg ~3.5 entries; replaces bulk memset)
    for (int j = offs + c; j < offs + 8 * b; ++j) epk[j] = 0u;
  }
}

// Phase C with 4-edge phase-split batching: 4 cols -> 4 independent srcinfo
// gathers in flight -> 4 LDS-atomic+stores. Zero device atomics.
__global__ __launch_bounds__(1024) void k_fillC(const int* __restrict__ ei,
                                                const float* __restrict__ ew,
                                                const u16* __restrict__ cntmat,
                                                const int* __restrict__ cnt,
                                                const int* __restrict__ ebase_n,
                                                const float* __restrict__ dinv_n,
                                                const int2* __restrict__ srcinfo,
                                                u32* __restrict__ epk) {
  __shared__ int lb[SLN];     // running global epk slot per dest node
  __shared__ int lim[SLN];    // slot cap (ebase + min(cnt,64))
  __shared__ float ldv[SLN];  // dest dinv
  int s = blockIdx.x & 7, b = blockIdx.x >> 3;
  int lo = s * SLN;
  int t = threadIdx.x;
  const u16* cm = cntmat + (size_t)blockIdx.x * SLN;
  for (int i = t; i < SLN; i += 1024) {
    int eb = ebase_n[lo + i];
    lb[i] = eb + (int)cm[i];
    lim[i] = eb + min(cnt[lo + i], ELLC);
    ldv[i] = dinv_n[lo + i];
  }
  __syncthreads();
  int e0 = b * CH_E;                 // CH_E = 25000, multiple of 4
  for (int e4 = e0 + t * 4; e4 < e0 + CH_E; e4 += 4096) {
    int4 c4 = *(const int4*)(ei + NE + e4);   // 16B-aligned (NE,e4 mult of 4)
    int4 r4 = *(const int4*)(ei + e4);
    float4 w4 = *(const float4*)(ew + e4);
    int cc[4] = {c4.x - lo, c4.y - lo, c4.z - lo, c4.w - lo};
    int rr[4] = {r4.x, r4.y, r4.z, r4.w};
    float wwv[4] = {w4.x, w4.y, w4.z, w4.w};
    int2 si[4];
#pragma unroll
    for (int u = 0; u < 4; ++u)
      if ((unsigned)cc[u] < (unsigned)SLN) si[u] = srcinfo[rr[u]];  // 4 in flight
#pragma unroll
    for (int u = 0; u < 4; ++u) {
      int c = cc[u];
      if ((unsigned)c < (unsigned)SLN) {
        float cf = __int_as_float(si[u].y) * wwv[u] * ldv[c];
        int slot = atomicAdd(&lb[c], 1);      // LDS atomic
        if (slot < lim[c]) {                  // safety; statistically never false
          _Float16 h = (_Float16)cf;
          u32 hb = (u32)*(u16*)&h;
          epk[slot] = (hb << 16) | (u32)(u16)si[u].x;
        }
      }
    }
  }
}

// ---------------- GEMM via MFMA: Yh[4][NN][32] (fp16) = X @ W ----------------
// 256 threads = 4 waves; block = 64 rows x 96 cols; wave = 16 rows x 6 tiles.
// PERM_DENSE: X is fp32 node-space via perm (layer 1); else fp16 sliced [4][NN][32].

template <int K, bool PERM_DENSE>
__global__ __launch_bounds__(256) void k_gemm(const void* __restrict__ Xv,
                                              const float* __restrict__ Wg,
                                              _Float16* __restrict__ Yh,
                                              const int* __restrict__ perm) {
  constexpr int LDA = K + 8;     // fp16 elems; (K+8)*2 bytes is a multiple of 16
  constexpr int LDO = 104;       // epilogue row stride (96+8) -> 208B, 16B-aligned
  __shared__ _Float16 sBuf[160 * LDA];   // [64][LDA] A  +  [96][LDA] W^T
  __shared__ int sPerm[64];
  _Float16* sA = sBuf;
  _Float16* sWt = sBuf + 64 * LDA;
  int tid = threadIdx.x;
  int wave = tid >> 6, lane = tid & 63;
  int n0 = blockIdx.x * 64;
  if (PERM_DENSE && tid < 64) {
    int nr = n0 + tid;
    sPerm[tid] = (nr < NN) ? perm[nr] : -1;
  }
  __syncthreads();  // sPerm visible to all stagers
  // stage W^T (fp32 -> fp16): read Wg[k][c] coalesced over c
  for (int i = tid; i < K * CH; i += 256) {
    int k = i / CH, c = i - k * CH;
    sWt[c * LDA + k] = (_Float16)Wg[i];
  }
  // stage A
  if constexpr (PERM_DENSE) {
    const float* Xf = (const float*)Xv;
    for (int i = tid; i < 64 * (K / 4); i += 256) {
      int r = i / (K / 4), c4 = i - r * (K / 4);
      float4 v = make_float4(0.f, 0.f, 0.f, 0.f);
      int row = sPerm[r];
      if (row >= 0) v = *(const float4*)(Xf + (size_t)row * K + c4 * 4);
      _Float16* d = &sA[r * LDA + c4 * 4];
      d[0] = (_Float16)v.x; d[1] = (_Float16)v.y;
      d[2] = (_Float16)v.z; d[3] = (_Float16)v.w;
    }
  } else {
    const _Float16* Xh = (const _Float16*)Xv;
    for (int i = tid; i < 64 * 12; i += 256) {  // K==96: 12 half8 chunks/row
      int r = i / 12, c8 = i - r * 12;
      int n = n0 + r;
      half8 v = (half8){0, 0, 0, 0, 0, 0, 0, 0};
      if (n < NN) {
        int sl = c8 / 3, off = (c8 - sl * 3) * 8;
        v = *(const half8*)(Xh + ((size_t)sl * NN + n) * 32 + off);
      }
      *(half8*)&sA[r * LDA + c8 * 8] = v;   // 16B store, aligned
    }
  }
  __syncthreads();
  // MFMA main: wave handles rows [wave*16, wave*16+16), 6 column tiles
  f32x4 acc[6];
#pragma unroll
  for (int t = 0; t < 6; ++t) acc[t] = (f32x4){0.f, 0.f, 0.f, 0.f};
  int arow = wave * 16 + (lane & 15);
  int koff = (lane >> 4) * 8;
#pragma unroll
  for (int k0 = 0; k0 < K; k0 += 32) {
    f16x8 af = *(const f16x8*)&sA[arow * LDA + k0 + koff];
#pragma unroll
    for (int t = 0; t < 6; ++t) {
      f16x8 bf = *(const f16x8*)&sWt[(t * 16 + (lane & 15)) * LDA + k0 + koff];
      acc[t] = __builtin_amdgcn_mfma_f32_16x16x32_f16(af, bf, acc[t], 0, 0, 0);
    }
  }
  __syncthreads();  // done reading sWt; reuse it as epilogue buffer
  _Float16* sOut = sWt;  // [64][LDO]
#pragma unroll
  for (int t = 0; t < 6; ++t) {
#pragma unroll
    for (int i = 0; i < 4; ++i) {
      int row = wave * 16 + (lane >> 4) * 4 + i;
      int col = t * 16 + (lane & 15);
      sOut[row * LDO + col] = (_Float16)acc[t][i];
    }
  }
  __syncthreads();
  // sliced stores: 12 chunks of 8 cols per row
  for (int idx = tid; idx < 64 * 12; idx += 256) {
    int r = idx & 63, c8 = idx >> 6;
    int n = n0 + r;
    if (n < NN) {
      int sl = c8 / 3, off = (c8 - sl * 3) * 8;
      half8 v = *(const half8*)&sOut[r * LDO + c8 * 8];
      *(half8*)(Yh + ((size_t)sl * NN + n) * 32 + off) = v;
    }
  }
}

// ---------------- aggregation (fp16 Y in, fp16 H out, 16-deep gather ILP) ----
// epk loads and Hh stores are NON-TEMPORAL: protect the Y-slice's L2 residency
// (Y 3.2MB + epk 2.4MB + Hh 1.6MB per XCD would exceed the 4MB L2 otherwise).

template <bool RELU>
__global__ __launch_bounds__(192) void k_agg(const _Float16* __restrict__ Yh,
                                             const int* __restrict__ offs_r,
                                             const int* __restrict__ cntr,
                                             const u32* __restrict__ epk,
                                             const float* __restrict__ dinv_r,
                                             const float* __restrict__ bias,
                                             _Float16* __restrict__ Hh) {
  int slice = blockIdx.x & 3;
  int nb = blockIdx.x >> 2;
  int tid = threadIdx.x;
  int nl = tid / 3;        // rank slot 0..63
  int fq = tid - nl * 3;   // half8 chunk 0..2 (8 features each)
  int n = nb * 64 + nl;    // rank
  if (n >= NN) return;
  const _Float16* Ys = Yh + (size_t)slice * NN * 32;
  float d = dinv_r[n];
  float sc = d * d;
  half8 sv = *(const half8*)(Ys + (size_t)n * 32 + fq * 8);
  float acc[8];
#pragma unroll
  for (int i = 0; i < 8; ++i) acc[i] = sc * (float)sv[i];
  int s = offs_r[n], e = s + cntr[n];  // multiple of 8, 32B-aligned starts
  int j = s;
  // 16-wide batches: 16 independent gathers in flight per lane
  for (; j + 16 <= e; j += 16) {
    i32x4 q0 = __builtin_nontemporal_load((const i32x4*)&epk[j]);
    i32x4 q1 = __builtin_nontemporal_load((const i32x4*)&epk[j + 4]);
    i32x4 q2 = __builtin_nontemporal_load((const i32x4*)&epk[j + 8]);
    i32x4 q3 = __builtin_nontemporal_load((const i32x4*)&epk[j + 12]);
    u32 pk[16] = {(u32)q0[0], (u32)q0[1], (u32)q0[2], (u32)q0[3],
                  (u32)q1[0], (u32)q1[1], (u32)q1[2], (u32)q1[3],
                  (u32)q2[0], (u32)q2[1], (u32)q2[2], (u32)q2[3],
                  (u32)q3[0], (u32)q3[1], (u32)q3[2], (u32)q3[3]};
    half8 yv[16];
#pragma unroll
    for (int u = 0; u < 16; ++u)
      yv[u] = *(const half8*)(Ys + (size_t)(pk[u] & 0xffffu) * 32 + fq * 8);
#pragma unroll
    for (int u = 0; u < 16; ++u) {
      u16 hb = (u16)(pk[u] >> 16);
      float cf = (float)*(_Float16*)&hb;
#pragma unroll
      for (int i = 0; i < 8; ++i) acc[i] += cf * (float)yv[u][i];
    }
  }
  // remainder: cntr % 16 is 0 or 8
  if (j < e) {
    i32x4 q0 = __builtin_nontemporal_load((const i32x4*)&epk[j]);
    i32x4 q1 = __builtin_nontemporal_load((const i32x4*)&epk[j + 4]);
    u32 pk[8] = {(u32)q0[0], (u32)q0[1], (u32)q0[2], (u32)q0[3],
                 (u32)q1[0], (u32)q1[1], (u32)q1[2], (u32)q1[3]};
    half8 yv[8];
#pragma unroll
    for (int u = 0; u < 8; ++u)
      yv[u] = *(const half8*)(Ys + (size_t)(pk[u] & 0xffffu) * 32 + fq * 8);
#pragma unroll
    for (int u = 0; u < 8; ++u) {
      u16 hb = (u16)(pk[u] >> 16);
      float cf = (float)*(_Float16*)&hb;
#pragma unroll
      for (int i = 0; i < 8; ++i) acc[i] += cf * (float)yv[u][i];
    }
  }
  const float* bp = bias + slice * 24 + fq * 8;
  float4 b0 = *(const float4*)bp, b1 = *(const float4*)(bp + 4);
  acc[0] += b0.x; acc[1] += b0.y; acc[2] += b0.z; acc[3] += b0.w;
  acc[4] += b1.x; acc[5] += b1.y; acc[6] += b1.z; acc[7] += b1.w;
  if (RELU) {
#pragma unroll
    for (int i = 0; i < 8; ++i) acc[i] = fmaxf(acc[i], 0.f);
  }
  half8 hv;
#pragma unroll
  for (int i = 0; i < 8; ++i) hv[i] = (_Float16)acc[i];
  __builtin_nontemporal_store(hv, (half8*)(Hh + ((size_t)slice * NN + n) * 32 + fq * 8));
}

// ---------------- fused pool + MLP ----------------
// one block per graph: 768 thr = 4 fslices x (64 node-slots x 3 fq).
// Pool into lmax[96] (sortable-uint LDS atomicMax), then MLP inline.

__global__ __launch_bounds__(768) void k_poolmlp(const _Float16* __restrict__ Hh,
                                                 const int* __restrict__ gstart,
                                                 const int* __restrict__ irank,
                                                 const float* __restrict__ Wl1,
                                                 const float* __restrict__ bl1,
                                                 const float* __restrict__ Wl2,
                                                 const float* __restrict__ bl2,
                                                 float* __restrict__ out) {
  __shared__ int sRank[64];
  __shared__ u32 lmax[CH];
  __shared__ float p[CH];
  __shared__ float hs[LH];
  int g = blockIdx.x;
  int tid = threadIdx.x;
  int fs = tid / 192, wi = tid - fs * 192;
  int nl = wi / 3, fq = wi - nl * 3;
  if (tid < CH) lmax[tid] = 0u;  // < key of any float (incl. -inf)
  int s = gstart[g], e = gstart[g + 1];
  float mx[8];
#pragma unroll
  for (int i = 0; i < 8; ++i) mx[i] = -3.4e38f;
  const _Float16* Hs = Hh + (size_t)fs * NN * 32;
  for (int base = s; base < e; base += 64) {
    __syncthreads();  // protect sRank from previous iteration's readers
    if (tid < 64 && base + tid < e) sRank[tid] = irank[base + tid];
    __syncthreads();
    if (base + nl < e) {
      int rank = sRank[nl];
      half8 v = *(const half8*)(Hs + (size_t)rank * 32 + fq * 8);
#pragma unroll
      for (int i = 0; i < 8; ++i) mx[i] = fmaxf(mx[i], (float)v[i]);
    }
  }
  __syncthreads();
#pragma unroll
  for (int i = 0; i < 8; ++i) {
    u32 b = __float_as_uint(mx[i]);
    u32 k = (b & 0x80000000u) ? ~b : (b | 0x80000000u);  // monotone key
    atomicMax(&lmax[fs * 24 + fq * 8 + i], k);
  }
  __syncthreads();
  if (tid < CH) {
    u32 k = lmax[tid];
    u32 b = (k & 0x80000000u) ? (k & 0x7fffffffu) : ~k;
    p[tid] = fmaxf(__uint_as_float(b), 0.f);  // relu(max) == max(relu)
  }
  __syncthreads();
  if (tid < LH) {
    float a = bl1[tid];
#pragma unroll 4
    for (int k = 0; k < CH; ++k) a += p[k] * Wl1[k * LH + tid];
    hs[tid] = fmaxf(a, 0.f);
  }
  __syncthreads();
  if (tid < NC) {
    float a = bl2[tid];
#pragma unroll 4
    for (int k = 0; k < LH; ++k) a += hs[k] * Wl2[k * NC + tid];
    out[g * NC + tid] = a;
  }
}

}  // namespace

extern "C" void kernel_launch(void* const* d_in, const int* in_sizes, int n_in,
                              void* d_out, int out_size, void* d_ws, size_t ws_size,
                              hipStream_t stream) {
  const float* x   = (const float*)d_in[0];
  const int*   ei  = (const int*)d_in[1];
  const float* ew  = (const float*)d_in[2];
  const int*   bat = (const int*)d_in[3];
  const float* W1  = (const float*)d_in[4];
  const float* b1  = (const float*)d_in[5];
  const float* W2  = (const float*)d_in[6];
  const float* b2  = (const float*)d_in[7];
  const float* W3  = (const float*)d_in[8];
  const float* b3  = (const float*)d_in[9];
  const float* Wl1 = (const float*)d_in[10];
  const float* bl1 = (const float*)d_in[11];
  const float* Wl2 = (const float*)d_in[12];
  const float* bl2 = (const float*)d_in[13];
  float* out = (float*)d_out;

  // workspace carve-up (256B aligned)
  char* base = (char*)d_ws;
  size_t o = 0;
  auto carve = [&](size_t bytes) {
    char* p = base + o;
    o = (o + bytes + 255) & ~(size_t)255;
    return p;
  };
  constexpr size_t NEP = (size_t)NE + 8 * (size_t)NN;  // padded CSR capacity
  int*   cnt     = (int*)carve(NN * 4);
  u16*   cntmat  = (u16*)carve((size_t)NSL * NBC * SLN * 2);    // 3.2MB (u16)
  float* wsummat = (float*)carve((size_t)NSL * NBC * SLN * 4);  // 6.4MB
  int*   hist2d  = (int*)carve((size_t)NSL * 64 * NBS * 4);
  int*   perm    = (int*)carve(NN * 4);
  int*   irank   = (int*)carve(NN * 4);
  int*   cntr    = (int*)carve(NN * 4);
  int*   offs_r  = (int*)carve(NN * 4);
  float* dinv_r  = (float*)carve(NN * 4);
  float* dinv_n  = (float*)carve(NN * 4);
  int*   ebase_n = (int*)carve(NN * 4);
  int2*  srcinfo = (int2*)carve((size_t)NN * 8);
  int*   gstart  = (int*)carve((NG + 1) * 4);
  u32*   epk     = (u32*)carve(NEP * 4);                   // packed CSR 4.8MB
  _Float16* Yh   = (_Float16*)carve((size_t)4 * NN * 32 * 2);  // [4][NN][32] fp16
  _Float16* Hh   = (_Float16*)carve((size_t)4 * NN * 32 * 2);  // [4][NN][32] fp16
  (void)ws_size; (void)n_in; (void)in_sizes; (void)out_size;

  const int GB_G = (NN + 63) / 64;           // 782 gemm blocks
  const int GB_A = 4 * ((NN + 63) / 64);     // 4 fslices x 782 rank-blocks

  // graph structure (shared by all 3 conv layers) — 4 kernels, no memset
  k_cntA<<<NSL * NBC, 1024, 0, stream>>>(ei, ew, cntmat, wsummat);
  k_cntB<<<NSL * NBS, 256, 0, stream>>>(cntmat, wsummat, cnt, dinv_n, hist2d,
                                        bat, gstart);
  k_place<<<NSL * NBS, 256, 0, stream>>>(cnt, hist2d, dinv_n, perm, irank, cntr,
                                         offs_r, dinv_r, ebase_n, srcinfo, epk);
  k_fillC<<<NSL * NBC, 1024, 0, stream>>>(ei, ew, cntmat, cnt, ebase_n, dinv_n,
                                          srcinfo, epk);

  // layer 1 (dense node-space input x, perm-gathered)
  k_gemm<FIN, true><<<GB_G, 256, 0, stream>>>(x, W1, Yh, perm);
  k_agg<true><<<GB_A, 192, 0, stream>>>(Yh, offs_r, cntr, epk, dinv_r, b1, Hh);
  // layer 2 (sliced fp16 rank-space input Hh)
  k_gemm<CH, false><<<GB_G, 256, 0, stream>>>(Hh, W2, Yh, perm);
  k_agg<true><<<GB_A, 192, 0, stream>>>(Yh, offs_r, cntr, epk, dinv_r, b2, Hh);
  // layer 3
  k_gemm<CH, false><<<GB_G, 256, 0, stream>>>(Hh, W3, Yh, perm);
  k_agg<false><<<GB_A, 192, 0, stream>>>(Yh, offs_r, cntr, epk, dinv_r, b3, Hh);

  // fused pool + MLP
  k_poolmlp<<<NG, 768, 0, stream>>>(Hh, gstart, irank, Wl1, bl1, Wl2, bl2, out);
}

// Round 27
// 204.065 us; speedup vs baseline: 1.2302x; 1.2302x over previous
//
#include <hip/hip_runtime.h>
#include <math.h>

namespace {

constexpr int NN  = 50000;   // nodes
constexpr int NE  = 800000;  // edges
constexpr int FIN = 128;     // in features
constexpr int CH  = 96;      // conv hidden
constexpr int LH  = 64;      // lin hidden
constexpr int NC  = 10;      // classes
constexpr int NG  = 128;     // graphs
constexpr int ELLC = 64;     // per-node edge cap (P[deg>64] ~ 1e-15 for Poisson(16))
constexpr int NSL  = 8;      // dest slices (one per XCD)
constexpr int SLN  = NN / NSL;              // 6250 nodes per slice (exact)
constexpr int NBS  = (SLN + 255) / 256;     // 25 node-blocks per slice
constexpr int NBC  = 32;     // edge chunks per slice
constexpr int CH_E = NE / NBC;              // 25000 edges per chunk (exact)

typedef unsigned short u16;
typedef unsigned int u32;
typedef __attribute__((ext_vector_type(8))) _Float16 half8;
typedef __attribute__((ext_vector_type(8))) _Float16 f16x8;
typedef __attribute__((ext_vector_type(4))) float f32x4;

__device__ __forceinline__ int round8(int c) { return (c + 7) & ~7; }
__device__ __forceinline__ int bucket_of(int craw) { return min(round8(craw) >> 3, 63); }

// ---------------- graph-structure build (once per call) ----------------
// Atomic-free, slice-major rank space. cntmat planes are u16 (counts <= 64).

__global__ __launch_bounds__(1024) void k_cntA(const int* __restrict__ ei,
                                               const float* __restrict__ ew,
                                               u16* __restrict__ cntmat,
                                               float* __restrict__ wsummat) {
  __shared__ int lh[SLN];
  __shared__ float lw[SLN];
  int s = blockIdx.x & 7, b = blockIdx.x >> 3;
  int lo = s * SLN;
  int t = threadIdx.x;
  for (int i = t; i < SLN; i += 1024) { lh[i] = 0; lw[i] = 0.f; }
  __syncthreads();
  int e0 = b * CH_E, e1 = e0 + CH_E;
  for (int e = e0 + t; e < e1; e += 1024) {
    int c = ei[NE + e] - lo;
    if ((unsigned)c < (unsigned)SLN) {
      atomicAdd(&lh[c], 1);        // LDS atomic
      atomicAdd(&lw[c], ew[e]);    // LDS float atomic
    }
  }
  __syncthreads();
  u16* dst = cntmat + (size_t)blockIdx.x * SLN;
  float* dw = wsummat + (size_t)blockIdx.x * SLN;
  for (int i = t; i < SLN; i += 1024) { dst[i] = (u16)lh[i]; dw[i] = lw[i]; }
}

__global__ void k_cntB(u16* __restrict__ cntmat, const float* __restrict__ wsummat,
                       int* __restrict__ cnt, float* __restrict__ dinv_n,
                       int* __restrict__ hist2d,
                       const int* __restrict__ batch, int* __restrict__ gstart) {
  __shared__ int lh[64];
  int s = blockIdx.x / NBS, blk = blockIdx.x - s * NBS;
  int t = threadIdx.x;
  if (t < 64) lh[t] = 0;
  __syncthreads();
  int i = blk * 256 + t;  // within slice
  if (i < SLN) {
    int n = s * SLN + i;
    int run = 0;
    float ws = 0.f;
    for (int b = 0; b < NBC; ++b) {
      size_t off = ((size_t)(b * 8 + s)) * SLN + i;
      int v = cntmat[off];
      cntmat[off] = (u16)min(run, 255);  // exclusive base (<=64 always)
      run += v;
      ws += wsummat[off];
    }
    cnt[n] = run;
    dinv_n[n] = 1.0f / sqrtf(1.0f + ws);  // self-loop weight 1; >= 1 always
    atomicAdd(&lh[bucket_of(min(run, ELLC))], 1);  // LDS atomic
    int g = batch[n];
    if (n == 0 || batch[n - 1] != g) gstart[g] = n;
    if (n == NN - 1) gstart[NG] = NN;
  }
  __syncthreads();
  if (t < 64) hist2d[(s * 64 + t) * NBS + blk] = lh[t];
}

__global__ __launch_bounds__(256) void k_place(const int* __restrict__ cnt,
                                               const int* __restrict__ hist2d,
                                               const float* __restrict__ dinv_n,
                                               int* __restrict__ perm,
                                               int* __restrict__ irank,
                                               int* __restrict__ cntr,
                                               int* __restrict__ offs_r,
                                               float* __restrict__ dinv_r,
                                               int* __restrict__ ebase_n,
                                               int2* __restrict__ srcinfo,
                                               u32* __restrict__ epk) {
  constexpr int TOT = NSL * 64 * NBS;  // 12800
  __shared__ int vals[TOT];            // 51.2KB
  __shared__ int tot[NSL][64];
  __shared__ int rankStartS[NSL][64];
  __shared__ int edgeBaseS[NSL][64];
  __shared__ int sliceEB[NSL];
  __shared__ int sB[64];
  __shared__ int lc[64];
  int s = blockIdx.x / NBS, blk = blockIdx.x - s * NBS;
  int t = threadIdx.x;
  if (t < 64) lc[t] = 0;
  for (int i = t; i < TOT; i += 256) vals[i] = hist2d[i];
  __syncthreads();
  if (t < 64) {
    for (int ss = 0; ss < NSL; ++ss) {
      int v = 0;
      for (int k = 0; k < NBS; ++k) v += vals[(ss * 64 + t) * NBS + k];
      tot[ss][t] = v;
    }
  }
  __syncthreads();
  if (t < NSL) {
    int run = 0, erun = 0;
    for (int b = 0; b < 64; ++b) {
      rankStartS[t][b] = run;
      edgeBaseS[t][b] = erun;
      run += tot[t][b];
      erun += 8 * b * tot[t][b];
    }
    sliceEB[t] = erun;  // total padded edges of slice t (temp)
  }
  __syncthreads();
  if (t == 0) {
    int run = 0;
    for (int ss = 0; ss < NSL; ++ss) { int v = sliceEB[ss]; sliceEB[ss] = run; run += v; }
  }
  if (t < 64) {
    int v = rankStartS[s][t];
    for (int k = 0; k < blk; ++k) v += vals[(s * 64 + t) * NBS + k];
    sB[t] = v;  // this block's within-slice rank start for bucket t
  }
  __syncthreads();
  int i = blk * 256 + t;
  if (i < SLN) {
    int n = s * SLN + i;
    int c = min(cnt[n], ELLC);
    int b = bucket_of(c);
    int r = atomicAdd(&lc[b], 1);             // LDS atomic
    int wr = sB[b] + r;                       // within-slice rank
    int rank = s * SLN + wr;
    int offs = sliceEB[s] + edgeBaseS[s][b] + 8 * b * (wr - rankStartS[s][b]);
    perm[rank] = n;
    irank[n] = rank;
    cntr[rank] = 8 * b;                       // == round8(c)
    offs_r[rank] = offs;
    dinv_r[rank] = dinv_n[n];
    ebase_n[n] = offs;
    srcinfo[n] = make_int2(rank, __float_as_int(dinv_n[n]));
    // zero this node's pad slots (avg ~3.5 entries; replaces bulk memset)
    for (int j = offs + c; j < offs + 8 * b; ++j) epk[j] = 0u;
  }
}

// Phase C with 4-edge phase-split batching: 4 cols -> 4 independent srcinfo
// gathers in flight -> 4 LDS-atomic+stores. Zero device atomics.
__global__ __launch_bounds__(1024) void k_fillC(const int* __restrict__ ei,
                                                const float* __restrict__ ew,
                                                const u16* __restrict__ cntmat,
                                                const int* __restrict__ cnt,
                                                const int* __restrict__ ebase_n,
                                                const float* __restrict__ dinv_n,
                                                const int2* __restrict__ srcinfo,
                                                u32* __restrict__ epk) {
  __shared__ int lb[SLN];     // running global epk slot per dest node
  __shared__ int lim[SLN];    // slot cap (ebase + min(cnt,64))
  __shared__ float ldv[SLN];  // dest dinv
  int s = blockIdx.x & 7, b = blockIdx.x >> 3;
  int lo = s * SLN;
  int t = threadIdx.x;
  const u16* cm = cntmat + (size_t)blockIdx.x * SLN;
  for (int i = t; i < SLN; i += 1024) {
    int eb = ebase_n[lo + i];
    lb[i] = eb + (int)cm[i];
    lim[i] = eb + min(cnt[lo + i], ELLC);
    ldv[i] = dinv_n[lo + i];
  }
  __syncthreads();
  int e0 = b * CH_E;                 // CH_E = 25000, multiple of 4
  for (int e4 = e0 + t * 4; e4 < e0 + CH_E; e4 += 4096) {
    int4 c4 = *(const int4*)(ei + NE + e4);   // 16B-aligned (NE,e4 mult of 4)
    int4 r4 = *(const int4*)(ei + e4);
    float4 w4 = *(const float4*)(ew + e4);
    int cc[4] = {c4.x - lo, c4.y - lo, c4.z - lo, c4.w - lo};
    int rr[4] = {r4.x, r4.y, r4.z, r4.w};
    float wwv[4] = {w4.x, w4.y, w4.z, w4.w};
    int2 si[4];
#pragma unroll
    for (int u = 0; u < 4; ++u)
      if ((unsigned)cc[u] < (unsigned)SLN) si[u] = srcinfo[rr[u]];  // 4 in flight
#pragma unroll
    for (int u = 0; u < 4; ++u) {
      int c = cc[u];
      if ((unsigned)c < (unsigned)SLN) {
        float cf = __int_as_float(si[u].y) * wwv[u] * ldv[c];
        int slot = atomicAdd(&lb[c], 1);      // LDS atomic
        if (slot < lim[c]) {                  // safety; statistically never false
          _Float16 h = (_Float16)cf;
          u32 hb = (u32)*(u16*)&h;
          epk[slot] = (hb << 16) | (u32)(u16)si[u].x;
        }
      }
    }
  }
}

// ---------------- GEMM via MFMA: Yh[4][NN][32] (fp16) = X @ W ----------------
// 256 threads = 4 waves; block = 64 rows x 96 cols; wave = 16 rows x 6 tiles.
// PERM_DENSE: X is fp32 node-space via perm (layer 1); else fp16 sliced [4][NN][32].

template <int K, bool PERM_DENSE>
__global__ __launch_bounds__(256) void k_gemm(const void* __restrict__ Xv,
                                              const float* __restrict__ Wg,
                                              _Float16* __restrict__ Yh,
                                              const int* __restrict__ perm) {
  constexpr int LDA = K + 8;     // fp16 elems; (K+8)*2 bytes is a multiple of 16
  constexpr int LDO = 104;       // epilogue row stride (96+8) -> 208B, 16B-aligned
  __shared__ _Float16 sBuf[160 * LDA];   // [64][LDA] A  +  [96][LDA] W^T
  __shared__ int sPerm[64];
  _Float16* sA = sBuf;
  _Float16* sWt = sBuf + 64 * LDA;
  int tid = threadIdx.x;
  int wave = tid >> 6, lane = tid & 63;
  int n0 = blockIdx.x * 64;
  if (PERM_DENSE && tid < 64) {
    int nr = n0 + tid;
    sPerm[tid] = (nr < NN) ? perm[nr] : -1;
  }
  __syncthreads();  // sPerm visible to all stagers
  // stage W^T (fp32 -> fp16): read Wg[k][c] coalesced over c
  for (int i = tid; i < K * CH; i += 256) {
    int k = i / CH, c = i - k * CH;
    sWt[c * LDA + k] = (_Float16)Wg[i];
  }
  // stage A
  if constexpr (PERM_DENSE) {
    const float* Xf = (const float*)Xv;
    for (int i = tid; i < 64 * (K / 4); i += 256) {
      int r = i / (K / 4), c4 = i - r * (K / 4);
      float4 v = make_float4(0.f, 0.f, 0.f, 0.f);
      int row = sPerm[r];
      if (row >= 0) v = *(const float4*)(Xf + (size_t)row * K + c4 * 4);
      _Float16* d = &sA[r * LDA + c4 * 4];
      d[0] = (_Float16)v.x; d[1] = (_Float16)v.y;
      d[2] = (_Float16)v.z; d[3] = (_Float16)v.w;
    }
  } else {
    const _Float16* Xh = (const _Float16*)Xv;
    for (int i = tid; i < 64 * 12; i += 256) {  // K==96: 12 half8 chunks/row
      int r = i / 12, c8 = i - r * 12;
      int n = n0 + r;
      half8 v = (half8){0, 0, 0, 0, 0, 0, 0, 0};
      if (n < NN) {
        int sl = c8 / 3, off = (c8 - sl * 3) * 8;
        v = *(const half8*)(Xh + ((size_t)sl * NN + n) * 32 + off);
      }
      *(half8*)&sA[r * LDA + c8 * 8] = v;   // 16B store, aligned
    }
  }
  __syncthreads();
  // MFMA main: wave handles rows [wave*16, wave*16+16), 6 column tiles
  f32x4 acc[6];
#pragma unroll
  for (int t = 0; t < 6; ++t) acc[t] = (f32x4){0.f, 0.f, 0.f, 0.f};
  int arow = wave * 16 + (lane & 15);
  int koff = (lane >> 4) * 8;
#pragma unroll
  for (int k0 = 0; k0 < K; k0 += 32) {
    f16x8 af = *(const f16x8*)&sA[arow * LDA + k0 + koff];
#pragma unroll
    for (int t = 0; t < 6; ++t) {
      f16x8 bf = *(const f16x8*)&sWt[(t * 16 + (lane & 15)) * LDA + k0 + koff];
      acc[t] = __builtin_amdgcn_mfma_f32_16x16x32_f16(af, bf, acc[t], 0, 0, 0);
    }
  }
  __syncthreads();  // done reading sWt; reuse it as epilogue buffer
  _Float16* sOut = sWt;  // [64][LDO]
#pragma unroll
  for (int t = 0; t < 6; ++t) {
#pragma unroll
    for (int i = 0; i < 4; ++i) {
      int row = wave * 16 + (lane >> 4) * 4 + i;
      int col = t * 16 + (lane & 15);
      sOut[row * LDO + col] = (_Float16)acc[t][i];
    }
  }
  __syncthreads();
  // sliced stores: 12 chunks of 8 cols per row
  for (int idx = tid; idx < 64 * 12; idx += 256) {
    int r = idx & 63, c8 = idx >> 6;
    int n = n0 + r;
    if (n < NN) {
      int sl = c8 / 3, off = (c8 - sl * 3) * 8;
      half8 v = *(const half8*)&sOut[r * LDO + c8 * 8];
      *(half8*)(Yh + ((size_t)sl * NN + n) * 32 + off) = v;
    }
  }
}

// ---------------- aggregation (fp16 Y in, fp16 H out, 16-deep gather ILP) ----

template <bool RELU>
__global__ __launch_bounds__(192) void k_agg(const _Float16* __restrict__ Yh,
                                             const int* __restrict__ offs_r,
                                             const int* __restrict__ cntr,
                                             const u32* __restrict__ epk,
                                             const float* __restrict__ dinv_r,
                                             const float* __restrict__ bias,
                                             _Float16* __restrict__ Hh) {
  int slice = blockIdx.x & 3;
  int nb = blockIdx.x >> 2;
  int tid = threadIdx.x;
  int nl = tid / 3;        // rank slot 0..63
  int fq = tid - nl * 3;   // half8 chunk 0..2 (8 features each)
  int n = nb * 64 + nl;    // rank
  if (n >= NN) return;
  const _Float16* Ys = Yh + (size_t)slice * NN * 32;
  float d = dinv_r[n];
  float sc = d * d;
  half8 sv = *(const half8*)(Ys + (size_t)n * 32 + fq * 8);
  float acc[8];
#pragma unroll
  for (int i = 0; i < 8; ++i) acc[i] = sc * (float)sv[i];
  int s = offs_r[n], e = s + cntr[n];  // multiple of 8, 32B-aligned starts
  int j = s;
  // 16-wide batches: 16 independent gathers in flight per lane
  for (; j + 16 <= e; j += 16) {
    int4 q0 = *(const int4*)&epk[j];
    int4 q1 = *(const int4*)&epk[j + 4];
    int4 q2 = *(const int4*)&epk[j + 8];
    int4 q3 = *(const int4*)&epk[j + 12];
    u32 pk[16] = {(u32)q0.x, (u32)q0.y, (u32)q0.z, (u32)q0.w,
                  (u32)q1.x, (u32)q1.y, (u32)q1.z, (u32)q1.w,
                  (u32)q2.x, (u32)q2.y, (u32)q2.z, (u32)q2.w,
                  (u32)q3.x, (u32)q3.y, (u32)q3.z, (u32)q3.w};
    half8 yv[16];
#pragma unroll
    for (int u = 0; u < 16; ++u)
      yv[u] = *(const half8*)(Ys + (size_t)(pk[u] & 0xffffu) * 32 + fq * 8);
#pragma unroll
    for (int u = 0; u < 16; ++u) {
      u16 hb = (u16)(pk[u] >> 16);
      float cf = (float)*(_Float16*)&hb;
#pragma unroll
      for (int i = 0; i < 8; ++i) acc[i] += cf * (float)yv[u][i];
    }
  }
  // remainder: cntr % 16 is 0 or 8
  if (j < e) {
    int4 q0 = *(const int4*)&epk[j];
    int4 q1 = *(const int4*)&epk[j + 4];
    u32 pk[8] = {(u32)q0.x, (u32)q0.y, (u32)q0.z, (u32)q0.w,
                 (u32)q1.x, (u32)q1.y, (u32)q1.z, (u32)q1.w};
    half8 yv[8];
#pragma unroll
    for (int u = 0; u < 8; ++u)
      yv[u] = *(const half8*)(Ys + (size_t)(pk[u] & 0xffffu) * 32 + fq * 8);
#pragma unroll
    for (int u = 0; u < 8; ++u) {
      u16 hb = (u16)(pk[u] >> 16);
      float cf = (float)*(_Float16*)&hb;
#pragma unroll
      for (int i = 0; i < 8; ++i) acc[i] += cf * (float)yv[u][i];
    }
  }
  const float* bp = bias + slice * 24 + fq * 8;
  float4 b0 = *(const float4*)bp, b1 = *(const float4*)(bp + 4);
  acc[0] += b0.x; acc[1] += b0.y; acc[2] += b0.z; acc[3] += b0.w;
  acc[4] += b1.x; acc[5] += b1.y; acc[6] += b1.z; acc[7] += b1.w;
  if (RELU) {
#pragma unroll
    for (int i = 0; i < 8; ++i) acc[i] = fmaxf(acc[i], 0.f);
  }
  half8 hv;
#pragma unroll
  for (int i = 0; i < 8; ++i) hv[i] = (_Float16)acc[i];
  *(half8*)(Hh + ((size_t)slice * NN + n) * 32 + fq * 8) = hv;
}

// ---------------- fused pool + MLP ----------------
// one block per graph: 768 thr = 4 fslices x (64 node-slots x 3 fq).
// Pool into lmax[96] (sortable-uint LDS atomicMax), then MLP inline.

__global__ __launch_bounds__(768) void k_poolmlp(const _Float16* __restrict__ Hh,
                                                 const int* __restrict__ gstart,
                                                 const int* __restrict__ irank,
                                                 const float* __restrict__ Wl1,
                                                 const float* __restrict__ bl1,
                                                 const float* __restrict__ Wl2,
                                                 const float* __restrict__ bl2,
                                                 float* __restrict__ out) {
  __shared__ int sRank[64];
  __shared__ u32 lmax[CH];
  __shared__ float p[CH];
  __shared__ float hs[LH];
  int g = blockIdx.x;
  int tid = threadIdx.x;
  int fs = tid / 192, wi = tid - fs * 192;
  int nl = wi / 3, fq = wi - nl * 3;
  if (tid < CH) lmax[tid] = 0u;  // < key of any float (incl. -inf)
  int s = gstart[g], e = gstart[g + 1];
  float mx[8];
#pragma unroll
  for (int i = 0; i < 8; ++i) mx[i] = -3.4e38f;
  const _Float16* Hs = Hh + (size_t)fs * NN * 32;
  for (int base = s; base < e; base += 64) {
    __syncthreads();  // protect sRank from previous iteration's readers
    if (tid < 64 && base + tid < e) sRank[tid] = irank[base + tid];
    __syncthreads();
    if (base + nl < e) {
      int rank = sRank[nl];
      half8 v = *(const half8*)(Hs + (size_t)rank * 32 + fq * 8);
#pragma unroll
      for (int i = 0; i < 8; ++i) mx[i] = fmaxf(mx[i], (float)v[i]);
    }
  }
  __syncthreads();
#pragma unroll
  for (int i = 0; i < 8; ++i) {
    u32 b = __float_as_uint(mx[i]);
    u32 k = (b & 0x80000000u) ? ~b : (b | 0x80000000u);  // monotone key
    atomicMax(&lmax[fs * 24 + fq * 8 + i], k);
  }
  __syncthreads();
  if (tid < CH) {
    u32 k = lmax[tid];
    u32 b = (k & 0x80000000u) ? (k & 0x7fffffffu) : ~k;
    p[tid] = fmaxf(__uint_as_float(b), 0.f);  // relu(max) == max(relu)
  }
  __syncthreads();
  if (tid < LH) {
    float a = bl1[tid];
#pragma unroll 4
    for (int k = 0; k < CH; ++k) a += p[k] * Wl1[k * LH + tid];
    hs[tid] = fmaxf(a, 0.f);
  }
  __syncthreads();
  if (tid < NC) {
    float a = bl2[tid];
#pragma unroll 4
    for (int k = 0; k < LH; ++k) a += hs[k] * Wl2[k * NC + tid];
    out[g * NC + tid] = a;
  }
}

}  // namespace

extern "C" void kernel_launch(void* const* d_in, const int* in_sizes, int n_in,
                              void* d_out, int out_size, void* d_ws, size_t ws_size,
                              hipStream_t stream) {
  const float* x   = (const float*)d_in[0];
  const int*   ei  = (const int*)d_in[1];
  const float* ew  = (const float*)d_in[2];
  const int*   bat = (const int*)d_in[3];
  const float* W1  = (const float*)d_in[4];
  const float* b1  = (const float*)d_in[5];
  const float* W2  = (const float*)d_in[6];
  const float* b2  = (const float*)d_in[7];
  const float* W3  = (const float*)d_in[8];
  const float* b3  = (const float*)d_in[9];
  const float* Wl1 = (const float*)d_in[10];
  const float* bl1 = (const float*)d_in[11];
  const float* Wl2 = (const float*)d_in[12];
  const float* bl2 = (const float*)d_in[13];
  float* out = (float*)d_out;

  // workspace carve-up (256B aligned)
  char* base = (char*)d_ws;
  size_t o = 0;
  auto carve = [&](size_t bytes) {
    char* p = base + o;
    o = (o + bytes + 255) & ~(size_t)255;
    return p;
  };
  constexpr size_t NEP = (size_t)NE + 8 * (size_t)NN;  // padded CSR capacity
  int*   cnt     = (int*)carve(NN * 4);
  u16*   cntmat  = (u16*)carve((size_t)NSL * NBC * SLN * 2);    // 3.2MB (u16)
  float* wsummat = (float*)carve((size_t)NSL * NBC * SLN * 4);  // 6.4MB
  int*   hist2d  = (int*)carve((size_t)NSL * 64 * NBS * 4);
  int*   perm    = (int*)carve(NN * 4);
  int*   irank   = (int*)carve(NN * 4);
  int*   cntr    = (int*)carve(NN * 4);
  int*   offs_r  = (int*)carve(NN * 4);
  float* dinv_r  = (float*)carve(NN * 4);
  float* dinv_n  = (float*)carve(NN * 4);
  int*   ebase_n = (int*)carve(NN * 4);
  int2*  srcinfo = (int2*)carve((size_t)NN * 8);
  int*   gstart  = (int*)carve((NG + 1) * 4);
  u32*   epk     = (u32*)carve(NEP * 4);                   // packed CSR 4.8MB
  _Float16* Yh   = (_Float16*)carve((size_t)4 * NN * 32 * 2);  // [4][NN][32] fp16
  _Float16* Hh   = (_Float16*)carve((size_t)4 * NN * 32 * 2);  // [4][NN][32] fp16
  (void)ws_size; (void)n_in; (void)in_sizes; (void)out_size;

  const int GB_G = (NN + 63) / 64;           // 782 gemm blocks
  const int GB_A = 4 * ((NN + 63) / 64);     // 4 fslices x 782 rank-blocks

  // graph structure (shared by all 3 conv layers) — 4 kernels, no memset
  k_cntA<<<NSL * NBC, 1024, 0, stream>>>(ei, ew, cntmat, wsummat);
  k_cntB<<<NSL * NBS, 256, 0, stream>>>(cntmat, wsummat, cnt, dinv_n, hist2d,
                                        bat, gstart);
  k_place<<<NSL * NBS, 256, 0, stream>>>(cnt, hist2d, dinv_n, perm, irank, cntr,
                                         offs_r, dinv_r, ebase_n, srcinfo, epk);
  k_fillC<<<NSL * NBC, 1024, 0, stream>>>(ei, ew, cntmat, cnt, ebase_n, dinv_n,
                                          srcinfo, epk);

  // layer 1 (dense node-space input x, perm-gathered)
  k_gemm<FIN, true><<<GB_G, 256, 0, stream>>>(x, W1, Yh, perm);
  k_agg<true><<<GB_A, 192, 0, stream>>>(Yh, offs_r, cntr, epk, dinv_r, b1, Hh);
  // layer 2 (sliced fp16 rank-space input Hh)
  k_gemm<CH, false><<<GB_G, 256, 0, stream>>>(Hh, W2, Yh, perm);
  k_agg<true><<<GB_A, 192, 0, stream>>>(Yh, offs_r, cntr, epk, dinv_r, b2, Hh);
  // layer 3
  k_gemm<CH, false><<<GB_G, 256, 0, stream>>>(Hh, W3, Yh, perm);
  k_agg<false><<<GB_A, 192, 0, stream>>>(Yh, offs_r, cntr, epk, dinv_r, b3, Hh);

  // fused pool + MLP
  k_poolmlp<<<NG, 768, 0, stream>>>(Hh, gstart, irank, Wl1, bl1, Wl2, bl2, out);
}